// Round 7
// baseline (156.205 us; speedup 1.0000x reference)
//
#include <hip/hip_runtime.h>
#include <math.h>

#define NB 32
#define NL 512
#define NC 64
#define NG 3
#define NT 10000
#define NP 96
#define TOPM 20
#define M1 8      // per-lane per-chunk fp32 prefilter list
#define NCH 256   // t-chunks (250 real, 6 empty)
#define CHUNK 40
#define QK 16     // extracted per quarter (4 quarters -> 64 candidates)
#define NCAND 64
#define GSTR ((size_t)NT * NC * 4)  // float stride between g-planes

// ---------------------------------------------------------------------------
// Kernel A: qstat (8 waves over L-segments, LDS combine). R5/R6-proven body.
// ---------------------------------------------------------------------------
__global__ __launch_bounds__(512) void qstat_kernel(const float* __restrict__ x,
                                                    double* __restrict__ q) {
  __shared__ double s_sum[8][3][64], s_sq[8][3][64], s_abs[8][3][64];
  __shared__ double s_first[3][64], s_last[3][64];
  const int b = blockIdx.x, w = threadIdx.x >> 6, c = threadIdx.x & 63;
  const float* xp = x + (size_t)b * NL * NC + c;
  const int l0 = w * 64;
  double sum[3] = {0, 0, 0}, sumsq[3] = {0, 0, 0}, sumabs[3] = {0, 0, 0};
  double prev[3] = {0, 0, 0}, first[3] = {0, 0, 0};
  if (w > 0) {
    double e0 = xp[(l0 - 4) * NC], e1 = xp[(l0 - 3) * NC];
    double e2 = xp[(l0 - 2) * NC], e3 = xp[(l0 - 1) * NC];
    prev[2] = e3; prev[1] = (e2 + e3) * 0.5; prev[0] = (e0 + e1 + e2 + e3) * 0.25;
  }
  double acc2 = 0.0, acc4 = 0.0;
  for (int i = 0; i < 64; ++i) {
    const int l = l0 + i;
    double v = (double)xp[l * NC];
    sum[2] += v; sumsq[2] += v * v;
    if (l == 0) first[2] = v; else sumabs[2] += fabs(v - prev[2]);
    prev[2] = v;
    acc2 += v;
    if (l & 1) {
      double cur = acc2 * 0.5; acc2 = 0.0;
      sum[1] += cur; sumsq[1] += cur * cur;
      if (l == 1) first[1] = cur; else sumabs[1] += fabs(cur - prev[1]);
      prev[1] = cur;
    }
    acc4 += v;
    if ((l & 3) == 3) {
      double cur = acc4 * 0.25; acc4 = 0.0;
      sum[0] += cur; sumsq[0] += cur * cur;
      if (l == 3) first[0] = cur; else sumabs[0] += fabs(cur - prev[0]);
      prev[0] = cur;
    }
  }
  for (int g = 0; g < 3; ++g) {
    s_sum[w][g][c] = sum[g]; s_sq[w][g][c] = sumsq[g]; s_abs[w][g][c] = sumabs[g];
  }
  if (w == 0) { for (int g = 0; g < 3; ++g) s_first[g][c] = first[g]; }
  if (w == 7) { for (int g = 0; g < 3; ++g) s_last[g][c] = prev[g]; }
  __syncthreads();
  if (w == 0) {
    const double J[3] = {128.0, 256.0, 512.0};
    for (int g = 0; g < 3; ++g) {
      double S = 0, Q2 = 0, A = 0;
      for (int ww = 0; ww < 8; ++ww) {
        S += s_sum[ww][g][c]; Q2 += s_sq[ww][g][c]; A += s_abs[ww][g][c];
      }
      double mean = S / J[g];
      double var = Q2 / J[g] - mean * mean; if (var < 0.0) var = 0.0;
      double last = s_last[g][c];
      double s0 = mean - last;
      double s1 = sqrt(var);
      double s2 = (last - s_first[g][c]) * (1.0 / 511.0);
      double s3 = A * (1.0 / 511.0);
      double n = sqrt(s0 * s0 + s1 * s1 + s2 * s2 + s3 * s3);
      double inv = 1.0 / fmax(n, 1e-12);
      double* qp = q + ((((size_t)g * NB) + b) * NC + c) * 4;
      qp[0] = s0 * inv; qp[1] = s1 * inv; qp[2] = s2 * inv; qp[3] = s3 * inv;
    }
  }
}

__device__ __forceinline__ void insert8(float s, int ti, float val[M1], int idx[M1]) {
  float cv = s; int ci = ti;
#pragma unroll
  for (int m = 0; m < M1; ++m) {
    bool sw = cv > val[m];
    float tv = sw ? val[m] : cv; int tx = sw ? idx[m] : ci;
    val[m] = sw ? cv : val[m];   idx[m] = sw ? ci : idx[m];
    cv = tv; ci = tx;
  }
}

__device__ __forceinline__ float dot4(float4 a, float q0, float q1, float q2, float q3) {
  return q0 * a.x + q1 * a.y + q2 * a.z + q3 * a.w;
}
__device__ __forceinline__ float nrm4(float4 a) {
  float ss = a.x * a.x + a.y * a.y + a.z * a.z + a.w * a.w;
  return rsqrtf(ss < 1e-24f ? 1e-24f : ss);
}

// ---------------------------------------------------------------------------
// Kernel B: fp32 prefilter scan reading RAW pool_state with inline fp32
// normalization (no phat materialization). 1024-thr blocks = 16 waves = 16
// b's sharing one chunk stream via L1/L2; grid (2, NCH). Writes one 64-B
// candidate blob (8 val + 8 idx) per (row,chunk).
// ---------------------------------------------------------------------------
__global__ __launch_bounds__(1024, 4) void sim32_kernel(
    const float* __restrict__ ps, const double* __restrict__ q,
    float* __restrict__ cand) {
  const int wav = threadIdx.x >> 6;
  const int c = threadIdx.x & 63;
  const int b = blockIdx.x * 16 + wav;
  const int ch = blockIdx.y;
  float qv[12];
#pragma unroll
  for (int g = 0; g < 3; ++g) {
    const double* qp = q + ((((size_t)g * NB) + b) * NC + c) * 4;
#pragma unroll
    for (int j = 0; j < 4; ++j) qv[g * 4 + j] = (float)(qp[j] * (1.0 / 3.0));
  }
  float val[M1]; int idx[M1];
#pragma unroll
  for (int m = 0; m < M1; ++m) { val[m] = -1e30f; idx[m] = 0; }
  int t0 = ch * CHUNK;
  int t1 = t0 + CHUNK; if (t1 > NT) t1 = NT;
  for (int t = t0; t + 1 < t1; t += 2) {
    const size_t oA = ((size_t)t * NC + c) * 4;
    const size_t oB = oA + (size_t)NC * 4;
    const float4 a0 = *reinterpret_cast<const float4*>(ps + oA);
    const float4 a1 = *reinterpret_cast<const float4*>(ps + GSTR + oA);
    const float4 a2 = *reinterpret_cast<const float4*>(ps + 2 * GSTR + oA);
    const float4 b0 = *reinterpret_cast<const float4*>(ps + oB);
    const float4 b1 = *reinterpret_cast<const float4*>(ps + GSTR + oB);
    const float4 b2 = *reinterpret_cast<const float4*>(ps + 2 * GSTR + oB);
    float sA = dot4(a0, qv[0], qv[1], qv[2], qv[3]) * nrm4(a0) +
               dot4(a1, qv[4], qv[5], qv[6], qv[7]) * nrm4(a1) +
               dot4(a2, qv[8], qv[9], qv[10], qv[11]) * nrm4(a2);
    float sB = dot4(b0, qv[0], qv[1], qv[2], qv[3]) * nrm4(b0) +
               dot4(b1, qv[4], qv[5], qv[6], qv[7]) * nrm4(b1) +
               dot4(b2, qv[8], qv[9], qv[10], qv[11]) * nrm4(b2);
    if (sA > val[M1 - 1]) insert8(sA, t, val, idx);
    if (sB > val[M1 - 1]) insert8(sB, t + 1, val, idx);
  }
  float* bp = cand + ((((size_t)b * NC) + c) * NCH + ch) * 16;
  float4 f0 = make_float4(val[0], val[1], val[2], val[3]);
  float4 f1 = make_float4(val[4], val[5], val[6], val[7]);
  int4 j0 = make_int4(idx[0], idx[1], idx[2], idx[3]);
  int4 j1 = make_int4(idx[4], idx[5], idx[6], idx[7]);
  reinterpret_cast<float4*>(bp)[0] = f0;
  reinterpret_cast<float4*>(bp)[1] = f1;
  reinterpret_cast<int4*>(bp)[2] = j0;
  reinterpret_cast<int4*>(bp)[3] = j1;
}

// order-preserving fp32 -> u32 map; key = (v asc-map << 32) | (MAX - t)
// so u64-descending == (v desc, t asc). t unique per row => unique keys.
__device__ __forceinline__ unsigned long long mk_key(float v, int t) {
  unsigned u = __float_as_uint(v);
  u = (u & 0x80000000u) ? ~u : (u | 0x80000000u);
  return ((unsigned long long)u << 32) | (unsigned long long)(0xFFFFFFFFu - (unsigned)t);
}

// ---------------------------------------------------------------------------
// Kernel C: merge + fp64 rerank (validated arithmetic) + softmax + gather.
// 256 threads. Extraction: 2 waves, 4 parallel 32-lane quarters, u64-key shfl
// argmax. Gather: m-split across thread-halves (2x MLP), t-ascending order.
// ---------------------------------------------------------------------------
__global__ __launch_bounds__(256) void merge_gather_kernel(
    const float* __restrict__ cand, const float* __restrict__ ps,
    const double* __restrict__ q, const float* __restrict__ y,
    float* __restrict__ out) {
  const int c = blockIdx.x, b = blockIdx.y;
  __shared__ float v_s[NCH * M1];
  __shared__ int i_s[NCH * M1];
  __shared__ int ct_s[NCAND];
  __shared__ double rv_s[NCAND];
  __shared__ double m0_s, inv_s;
  __shared__ double e_s[TOPM];
  __shared__ int ts_s[TOPM];
  __shared__ float w2_s[TOPM];
  __shared__ int t2_s[TOPM];
  __shared__ float part_s[2][NP];
  const size_t row = (size_t)b * NC + c;
  const float4* blob = reinterpret_cast<const float4*>(cand + row * NCH * 16);
  for (int k = threadIdx.x; k < NCH * 4; k += 256) {
    float4 f = blob[k];
    const int ch = k >> 2, part = k & 3;
    if (part < 2) {
      const int o = ch * M1 + part * 4;
      v_s[o] = f.x; v_s[o + 1] = f.y; v_s[o + 2] = f.z; v_s[o + 3] = f.w;
    } else {
      const int o = ch * M1 + (part - 2) * 4;
      int4 j = *reinterpret_cast<int4*>(&f);
      i_s[o] = j.x; i_s[o + 1] = j.y; i_s[o + 2] = j.z; i_s[o + 3] = j.w;
    }
  }
  __syncthreads();
  // --- quarter extraction (waves 0-1): quarter = (w<<1)|(lane>>5) ---
  if (threadIdx.x < 128) {
    const int w = threadIdx.x >> 6, lane = threadIdx.x & 63;
    const int lane32 = lane & 31;
    const int qtr = (w << 1) | (lane >> 5);
    const int l0 = (qtr * 64 + lane32 * 2) * M1;
    const int l1 = l0 + M1;
    int p0 = 0, p1 = 0;
    unsigned long long k0 = mk_key(v_s[l0], i_s[l0]);
    unsigned long long k1 = mk_key(v_s[l1], i_s[l1]);
    for (int r = 0; r < QK; ++r) {
      unsigned long long me = k0 > k1 ? k0 : k1;
      unsigned long long km = me;
#pragma unroll
      for (int st = 1; st < 32; st <<= 1) {
        unsigned long long k2 = __shfl_xor(km, st);
        km = k2 > km ? k2 : km;
      }
      if (lane32 == r)
        ct_s[qtr * QK + r] = (int)(0xFFFFFFFFu - (unsigned)(km & 0xFFFFFFFFull));
      if (me == km) {  // unique keys -> exactly one owner
        if (k0 >= k1) {
          ++p0; k0 = (p0 < M1) ? mk_key(v_s[l0 + p0], i_s[l0 + p0]) : 0ull;
        } else {
          ++p1; k1 = (p1 < M1) ? mk_key(v_s[l1 + p1], i_s[l1 + p1]) : 0ull;
        }
      }
    }
  }
  __syncthreads();
  // --- fp64 re-score of 64 candidates (identical arithmetic to validated) ---
  double myv = -1e300; int myt = 0x7fffffff;
  if (threadIdx.x < NCAND) {
    myt = ct_s[threadIdx.x];
    double s = 0.0;
#pragma unroll
    for (int g = 0; g < 3; ++g) {
      const double* qp = q + ((((size_t)g * NB) + b) * NC + c) * 4;
      const float4 pv = *reinterpret_cast<const float4*>(
          ps + ((((size_t)g * NT) + myt) * NC + c) * 4);
      double pp0 = pv.x, pp1 = pv.y, pp2 = pv.z, pp3 = pv.w;
      double ss = pp0 * pp0 + pp1 * pp1 + pp2 * pp2 + pp3 * pp3;
      double dot = qp[0] * pp0 + qp[1] * pp1 + qp[2] * pp2 + qp[3] * pp3;
      s += dot / fmax(sqrt(ss), 1e-12);
    }
    myv = s * (1.0 / 3.0);
    rv_s[threadIdx.x] = myv;
  }
  __syncthreads();
  // --- rank by counting (v desc, t asc); ranks unique since t unique ---
  int rank = -1;
  if (threadIdx.x < NCAND) {
    rank = 0;
    for (int j = 0; j < NCAND; ++j) {
      double vj = rv_s[j]; int tj = ct_s[j];
      rank += (vj > myv) || (vj == myv && tj < myt);
    }
    if (rank == 0) m0_s = myv;
  }
  __syncthreads();
  if (rank >= 0 && rank < TOPM) { e_s[rank] = exp((myv - m0_s) * 10.0); ts_s[rank] = myt; }
  __syncthreads();
  if (threadIdx.x == 0) {
    double sum = 0.0;
#pragma unroll
    for (int m = 0; m < TOPM; ++m) sum += e_s[m];
    inv_s = 1.0 / sum;
  }
  __syncthreads();
  // --- emit top-20 sorted by t ascending (DRAM locality for the gather) ---
  if (threadIdx.x < TOPM) {
    const int t = ts_s[threadIdx.x];
    int pos = 0;
#pragma unroll
    for (int j = 0; j < TOPM; ++j) pos += (ts_s[j] < t);
    w2_s[pos] = (float)(e_s[threadIdx.x] * inv_s);
    t2_s[pos] = t;
  }
  __syncthreads();
  // --- gather: m-split across halves for 2x outstanding loads ---
  const int half = threadIdx.x >> 7;
  const int pp = threadIdx.x & 127;
  if (pp < NP) {
    float acc = 0.f;
    const float* yc = y + c;
#pragma unroll
    for (int m = 0; m < 10; ++m) {
      const int mm = half * 10 + m;
      acc += w2_s[mm] * yc[((size_t)t2_s[mm] * NP + pp) << 6];
    }
    part_s[half][pp] = acc;
  }
  __syncthreads();
  if (threadIdx.x < NP)
    out[(((size_t)b * NP) + threadIdx.x) * NC + c] =
        part_s[0][threadIdx.x] + part_s[1][threadIdx.x];
}

// ---------------------------------------------------------------------------
// Fallback (small ws): round-1-proven all-fp64 inline path.
// ---------------------------------------------------------------------------
__global__ __launch_bounds__(256) void sim_topk_inline_kernel(
    const float* __restrict__ ps, const double* __restrict__ q,
    double* __restrict__ cval, int* __restrict__ cidx, int nch, int chunk) {
  const int wav = threadIdx.x >> 6;
  const int c = threadIdx.x & 63;
  const int b = blockIdx.y * 4 + wav;
  const int ch = blockIdx.x;
  double qv[3][4];
#pragma unroll
  for (int g = 0; g < 3; ++g) {
    const double* qp = q + ((((size_t)g * NB) + b) * NC + c) * 4;
    qv[g][0] = qp[0]; qv[g][1] = qp[1]; qv[g][2] = qp[2]; qv[g][3] = qp[3];
  }
  double val[TOPM]; int idx[TOPM];
#pragma unroll
  for (int m = 0; m < TOPM; ++m) { val[m] = -1e300; idx[m] = 0; }
  int t0 = ch * chunk;
  int t1 = t0 + chunk; if (t1 > NT) t1 = NT;
  for (int t = t0; t < t1; ++t) {
    double s = 0.0;
#pragma unroll
    for (int g = 0; g < 3; ++g) {
      const float4 pv = *reinterpret_cast<const float4*>(
          ps + ((((size_t)g * NT) + t) * NC + c) * 4);
      double p0 = pv.x, p1 = pv.y, p2 = pv.z, p3 = pv.w;
      double ss = p0 * p0 + p1 * p1 + p2 * p2 + p3 * p3;
      double dot = qv[g][0] * p0 + qv[g][1] * p1 + qv[g][2] * p2 + qv[g][3] * p3;
      s += dot / fmax(sqrt(ss), 1e-12);
    }
    s *= (1.0 / 3.0);
    if (s > val[TOPM - 1]) {
      double cv = s; int ci = t;
#pragma unroll
      for (int m = 0; m < TOPM; ++m) {
        bool sw = cv > val[m];
        double tv = sw ? val[m] : cv; int ti = sw ? idx[m] : ci;
        val[m] = sw ? cv : val[m];    idx[m] = sw ? ci : idx[m];
        cv = tv; ci = ti;
      }
    }
  }
  double* vout = cval + ((((size_t)b * NC) + c) * nch + ch) * TOPM;
  int* iout = cidx + ((((size_t)b * NC) + c) * nch + ch) * TOPM;
#pragma unroll
  for (int m = 0; m < TOPM; ++m) { vout[m] = val[m]; iout[m] = idx[m]; }
}

__global__ __launch_bounds__(128) void merge_gather_old_kernel(
    const double* __restrict__ cval, const int* __restrict__ cidx,
    const float* __restrict__ y, float* __restrict__ out, int nch) {
  const int c = blockIdx.x;
  const int b = blockIdx.y;
  __shared__ float w_s[TOPM];
  __shared__ int i_s[TOPM];
  if (threadIdx.x == 0) {
    double val[TOPM]; int idx[TOPM];
#pragma unroll
    for (int m = 0; m < TOPM; ++m) { val[m] = -1e300; idx[m] = 0; }
    const double* vin = cval + (((size_t)b * NC) + c) * nch * TOPM;
    const int* iin = cidx + (((size_t)b * NC) + c) * nch * TOPM;
    for (int k = 0; k < nch; ++k) {
      const int base = k * TOPM;
      for (int m = 0; m < TOPM; ++m) {
        double s = vin[base + m];
        if (!(s > val[TOPM - 1])) break;
        double cv = s; int ci = iin[base + m];
#pragma unroll
        for (int mm = 0; mm < TOPM; ++mm) {
          bool sw = cv > val[mm];
          double tv = sw ? val[mm] : cv; int ti = sw ? idx[mm] : ci;
          val[mm] = sw ? cv : val[mm];   idx[mm] = sw ? ci : idx[mm];
          cv = tv; ci = ti;
        }
      }
    }
    double mx = val[0];
    double e[TOPM]; double sum = 0.0;
#pragma unroll
    for (int m = 0; m < TOPM; ++m) { e[m] = exp((val[m] - mx) * 10.0); sum += e[m]; }
    double inv = 1.0 / sum;
#pragma unroll
    for (int m = 0; m < TOPM; ++m) { w_s[m] = (float)(e[m] * inv); i_s[m] = idx[m]; }
  }
  __syncthreads();
  const int p = threadIdx.x;
  if (p < NP) {
    float acc = 0.f;
#pragma unroll
    for (int m = 0; m < TOPM; ++m)
      acc += w_s[m] * y[(((size_t)i_s[m]) * NP + p) * NC + c];
    out[(((size_t)b * NP) + p) * NC + c] = acc;
  }
}

extern "C" void kernel_launch(void* const* d_in, const int* in_sizes, int n_in,
                              void* d_out, int out_size, void* d_ws, size_t ws_size,
                              hipStream_t stream) {
  const float* x = (const float*)d_in[0];
  const float* ps = (const float*)d_in[1];
  const float* y = (const float*)d_in[2];
  float* out = (float*)d_out;
  char* ws = (char*)d_ws;

  const size_t qbytes = (size_t)NG * NB * NC * 4 * sizeof(double);      // 196,608
  const size_t candbytes = (size_t)NB * NC * NCH * 16 * sizeof(float);  // 33.55 MB

  double* qbuf = (double*)ws;

  if (ws_size >= qbytes + candbytes) {
    float* cand = (float*)(ws + qbytes);
    qstat_kernel<<<dim3(NB), dim3(512), 0, stream>>>(x, qbuf);
    sim32_kernel<<<dim3(NB / 16, NCH), dim3(1024), 0, stream>>>(ps, qbuf, cand);
    merge_gather_kernel<<<dim3(NC, NB), dim3(256), 0, stream>>>(cand, ps, qbuf, y, out);
  } else {
    // fallback: round-1-proven all-fp64 path
    qstat_kernel<<<dim3(NB), dim3(512), 0, stream>>>(x, qbuf);
    const size_t per_ch = (size_t)NB * NC * TOPM * (sizeof(double) + sizeof(int));
    int nch = 1;
    if (ws_size > qbytes) {
      size_t mc = (ws_size - qbytes) / per_ch;
      nch = mc < 32 ? (int)mc : 32;
      if (nch < 1) nch = 1;
    }
    const int chunk = (NT + nch - 1) / nch;
    double* cval = (double*)(ws + qbytes);
    int* cidx = (int*)((char*)cval + (size_t)NB * NC * nch * TOPM * sizeof(double));
    sim_topk_inline_kernel<<<dim3(nch, NB / 4), dim3(256), 0, stream>>>(
        ps, qbuf, cval, cidx, nch, chunk);
    merge_gather_old_kernel<<<dim3(NC, NB), dim3(128), 0, stream>>>(cval, cidx, y, out, nch);
  }
}